// Round 1
// baseline (255.850 us; speedup 1.0000x reference)
//
#include <hip/hip_runtime.h>
#include <hip/hip_bf16.h>
#include <math.h>

#define PIXELS 16384   // 4*64*64
#define C      128
#define KS     7
#define HEADS  4
#define HD     32      // head dim
#define QSCALE 0.17677669529663687f  // 32^-0.5

// ---------------------------------------------------------------------------
// Kernel 1: qkvh = x @ [qkv_w | g1_w] + [qkv_b | g1_b]; q cols scaled by QSCALE
// M=16384, K=128, N=448 (7 tiles of 64). grid=(7, 256), block=256.
// ---------------------------------------------------------------------------
__global__ __launch_bounds__(256) void gemm_qkvh(
    const float* __restrict__ x, const float* __restrict__ qkv_w,
    const float* __restrict__ qkv_b, const float* __restrict__ g1_w,
    const float* __restrict__ g1_b, float* __restrict__ qkvh)
{
    __shared__ float As[64 * 128];   // XOR-swizzled in f4 space
    __shared__ float Bs[128 * 64];
    const int nt = blockIdx.x;
    const int m0 = blockIdx.y * 64;
    const int tid = threadIdx.x;

    // Load A tile (64x128), f4, swizzled: f4col' = c4 ^ (row&7)
#pragma unroll
    for (int it = 0; it < 8; it++) {
        int idx = tid + it * 256;          // 2048 f4 total
        int row = idx >> 5, c4 = idx & 31;
        float4 v = *(const float4*)(x + (size_t)(m0 + row) * 128 + c4 * 4);
        *(float4*)(As + row * 128 + ((c4 ^ (row & 7)) << 2)) = v;
    }
    // Load B tile (128x64)
    if (nt < 6) {
#pragma unroll
        for (int it = 0; it < 8; it++) {
            int idx = tid + it * 256;
            int row = idx >> 4, c4 = idx & 15;
            *(float4*)(Bs + row * 64 + c4 * 4) =
                *(const float4*)(qkv_w + (size_t)row * 384 + nt * 64 + c4 * 4);
        }
    } else {
#pragma unroll
        for (int it = 0; it < 8; it++) {
            int idx = tid + it * 256;
            int row = idx >> 4, c4 = idx & 15;
            *(float4*)(Bs + row * 64 + c4 * 4) =
                *(const float4*)(g1_w + (size_t)row * 64 + c4 * 4);
        }
    }
    __syncthreads();

    const int ty = tid >> 4, tx = tid & 15;
    float acc[4][4] = {};
#pragma unroll 8
    for (int k4 = 0; k4 < 32; k4++) {
        float4 a[4], b[4];
#pragma unroll
        for (int mm = 0; mm < 4; mm++) {
            int m = ty * 4 + mm;
            a[mm] = *(const float4*)(As + m * 128 + ((k4 ^ (m & 7)) << 2));
        }
#pragma unroll
        for (int ii = 0; ii < 4; ii++)
            b[ii] = *(const float4*)(Bs + (k4 * 4 + ii) * 64 + tx * 4);
#pragma unroll
        for (int mm = 0; mm < 4; mm++) {
            float am[4] = {a[mm].x, a[mm].y, a[mm].z, a[mm].w};
#pragma unroll
            for (int ii = 0; ii < 4; ii++) {
                acc[mm][0] += am[ii] * b[ii].x;
                acc[mm][1] += am[ii] * b[ii].y;
                acc[mm][2] += am[ii] * b[ii].z;
                acc[mm][3] += am[ii] * b[ii].w;
            }
        }
    }

    // Epilogue: bias, q-scale for tiles 0..1
    const float qs = (nt < 2) ? QSCALE : 1.0f;
    float4 bias;
    if (nt < 6) bias = *(const float4*)(qkv_b + nt * 64 + tx * 4);
    else        bias = *(const float4*)(g1_b + tx * 4);
#pragma unroll
    for (int mm = 0; mm < 4; mm++) {
        int m = m0 + ty * 4 + mm;
        float4 o;
        o.x = (acc[mm][0] + bias.x) * qs;
        o.y = (acc[mm][1] + bias.y) * qs;
        o.z = (acc[mm][2] + bias.z) * qs;
        o.w = (acc[mm][3] + bias.w) * qs;
        *(float4*)(qkvh + (size_t)m * 448 + nt * 64 + tx * 4) = o;
    }
}

// ---------------------------------------------------------------------------
// Kernel 2: gate[p] = sigmoid(relu(hidden) . g2_w + g2_b). wave per pixel.
// grid = 4096, block = 256 (4 pixels/block)
// ---------------------------------------------------------------------------
__global__ __launch_bounds__(256) void gate_kernel(
    const float* __restrict__ qkvh, const float* __restrict__ g2_w,
    const float* __restrict__ g2_b, float* __restrict__ gate)
{
    const int tid = threadIdx.x;
    const int lane = tid & 63;
    const int p = blockIdx.x * 4 + (tid >> 6);
    float h = qkvh[(size_t)p * 448 + 384 + lane];
    float v = fmaxf(h, 0.0f) * g2_w[lane];
#pragma unroll
    for (int off = 32; off >= 1; off >>= 1) v += __shfl_xor(v, off);
    if (lane == 0) {
        float g = v + g2_b[0];
        gate[p] = 1.0f / (1.0f + __expf(-g));
    }
}

// ---------------------------------------------------------------------------
// Kernel 3: neighborhood attention. block per pixel, wave per head.
// ---------------------------------------------------------------------------
__global__ __launch_bounds__(256) void attn_kernel(
    const float* __restrict__ qkvh, const float* __restrict__ rpb,
    float* __restrict__ attn_out)
{
    __shared__ float kv[49 * 260];    // per neighbor: [k(128) | v(128)], stride 260
    __shared__ float q_lds[128];
    __shared__ float attn_lds[4 * 64];

    const int p = blockIdx.x;
    const int b = p >> 12;
    const int rem = p & 4095;
    const int i = rem >> 6, j = rem & 63;
    int sh = i - 3; sh = sh < 0 ? 0 : (sh > 57 ? 57 : sh);
    int sw = j - 3; sw = sw < 0 ? 0 : (sw > 57 ? 57 : sw);
    const int tid = threadIdx.x;

    if (tid < 32) {
        float4 qv = *(const float4*)(qkvh + (size_t)p * 448 + tid * 4);
        *(float4*)(q_lds + tid * 4) = qv;   // already scaled in gemm epilogue
    }
    // stage 49 neighbors x 256 floats (k then v), f4
    for (int g = tid; g < 49 * 64; g += 256) {
        int l = g >> 6, c4 = g & 63;
        int ih = sh + l / 7, iw = sw + l % 7;
        float4 v = *(const float4*)(qkvh +
            ((size_t)((b * 64 + ih) * 64 + iw)) * 448 + 128 + c4 * 4);
        *(float4*)(kv + l * 260 + c4 * 4) = v;
    }
    __syncthreads();

    const int h = tid >> 6, lane = tid & 63;

    // scores + bias
    float s = -INFINITY;
    if (lane < 49) {
        int r = lane / 7, cc = lane % 7;
        int bih = sh + r - i + 6;
        int biw = sw + cc - j + 6;
        float acc = rpb[h * 169 + bih * 13 + biw];
        const float4* q4 = (const float4*)(q_lds + h * 32);
        const float4* k4 = (const float4*)(kv + lane * 260 + h * 32);
#pragma unroll
        for (int d4 = 0; d4 < 8; d4++) {
            float4 qv = q4[d4], kk = k4[d4];
            acc += qv.x * kk.x + qv.y * kk.y + qv.z * kk.z + qv.w * kk.w;
        }
        s = acc;
    }
    // wave softmax over 49 (lanes 49..63 hold -inf / 0)
    float m = s;
#pragma unroll
    for (int off = 32; off >= 1; off >>= 1) m = fmaxf(m, __shfl_xor(m, off));
    float e = (lane < 49) ? __expf(s - m) : 0.0f;
    float sum = e;
#pragma unroll
    for (int off = 32; off >= 1; off >>= 1) sum += __shfl_xor(sum, off);
    float a = e / sum;
    if (lane < 49) attn_lds[h * 64 + lane] = a;
    // wave-internal LDS: no cross-wave sharing, no barrier needed

    // PV: lane = lg*8 + d4; lane d4 covers dims 4*d4..4*d4+3
    const int d4 = lane & 7, lg = lane >> 3;
    float4 acc4 = {0.f, 0.f, 0.f, 0.f};
#pragma unroll
    for (int t = 0; t < 7; t++) {
        int l = lg + 8 * t;
        if (l < 49) {
            float av = attn_lds[h * 64 + l];
            float4 vv = *(const float4*)(kv + l * 260 + 128 + h * 32 + d4 * 4);
            acc4.x += av * vv.x; acc4.y += av * vv.y;
            acc4.z += av * vv.z; acc4.w += av * vv.w;
        }
    }
#pragma unroll
    for (int off = 8; off <= 32; off <<= 1) {
        acc4.x += __shfl_xor(acc4.x, off);
        acc4.y += __shfl_xor(acc4.y, off);
        acc4.z += __shfl_xor(acc4.z, off);
        acc4.w += __shfl_xor(acc4.w, off);
    }
    if (lg == 0)
        *(float4*)(attn_out + (size_t)p * 128 + h * 32 + d4 * 4) = acc4;
}

// ---------------------------------------------------------------------------
// Kernel 4: out = (attn_out @ proj_w + proj_b) * gate + x
// M=16384, K=128, N=128 (2 tiles). grid=(2,256), block=256.
// ---------------------------------------------------------------------------
__global__ __launch_bounds__(256) void gemm_proj(
    const float* __restrict__ attn_in, const float* __restrict__ proj_w,
    const float* __restrict__ proj_b, const float* __restrict__ gate,
    const float* __restrict__ x, float* __restrict__ out)
{
    __shared__ float As[64 * 128];
    __shared__ float Bs[128 * 64];
    const int nt = blockIdx.x;
    const int m0 = blockIdx.y * 64;
    const int tid = threadIdx.x;

#pragma unroll
    for (int it = 0; it < 8; it++) {
        int idx = tid + it * 256;
        int row = idx >> 5, c4 = idx & 31;
        float4 v = *(const float4*)(attn_in + (size_t)(m0 + row) * 128 + c4 * 4);
        *(float4*)(As + row * 128 + ((c4 ^ (row & 7)) << 2)) = v;
    }
#pragma unroll
    for (int it = 0; it < 8; it++) {
        int idx = tid + it * 256;
        int row = idx >> 4, c4 = idx & 15;
        *(float4*)(Bs + row * 64 + c4 * 4) =
            *(const float4*)(proj_w + (size_t)row * 128 + nt * 64 + c4 * 4);
    }
    __syncthreads();

    const int ty = tid >> 4, tx = tid & 15;
    float acc[4][4] = {};
#pragma unroll 8
    for (int k4 = 0; k4 < 32; k4++) {
        float4 a[4], b[4];
#pragma unroll
        for (int mm = 0; mm < 4; mm++) {
            int m = ty * 4 + mm;
            a[mm] = *(const float4*)(As + m * 128 + ((k4 ^ (m & 7)) << 2));
        }
#pragma unroll
        for (int ii = 0; ii < 4; ii++)
            b[ii] = *(const float4*)(Bs + (k4 * 4 + ii) * 64 + tx * 4);
#pragma unroll
        for (int mm = 0; mm < 4; mm++) {
            float am[4] = {a[mm].x, a[mm].y, a[mm].z, a[mm].w};
#pragma unroll
            for (int ii = 0; ii < 4; ii++) {
                acc[mm][0] += am[ii] * b[ii].x;
                acc[mm][1] += am[ii] * b[ii].y;
                acc[mm][2] += am[ii] * b[ii].z;
                acc[mm][3] += am[ii] * b[ii].w;
            }
        }
    }

    float4 bias = *(const float4*)(proj_b + nt * 64 + tx * 4);
#pragma unroll
    for (int mm = 0; mm < 4; mm++) {
        int m = m0 + ty * 4 + mm;
        float gv = gate[m];
        float4 xv = *(const float4*)(x + (size_t)m * 128 + nt * 64 + tx * 4);
        float4 o;
        o.x = (acc[mm][0] + bias.x) * gv + xv.x;
        o.y = (acc[mm][1] + bias.y) * gv + xv.y;
        o.z = (acc[mm][2] + bias.z) * gv + xv.z;
        o.w = (acc[mm][3] + bias.w) * gv + xv.w;
        *(float4*)(out + (size_t)m * 128 + nt * 64 + tx * 4) = o;
    }
}

// ---------------------------------------------------------------------------
extern "C" void kernel_launch(void* const* d_in, const int* in_sizes, int n_in,
                              void* d_out, int out_size, void* d_ws, size_t ws_size,
                              hipStream_t stream)
{
    const float* x      = (const float*)d_in[0];
    const float* qkv_w  = (const float*)d_in[1];
    const float* qkv_b  = (const float*)d_in[2];
    const float* proj_w = (const float*)d_in[3];
    const float* proj_b = (const float*)d_in[4];
    const float* rpb    = (const float*)d_in[5];
    const float* g1_w   = (const float*)d_in[6];
    const float* g1_b   = (const float*)d_in[7];
    const float* g2_w   = (const float*)d_in[8];
    const float* g2_b   = (const float*)d_in[9];
    float* out = (float*)d_out;

    float* ws       = (float*)d_ws;
    float* qkvh     = ws;                        // 16384*448 = 7,340,032 floats
    float* gate     = ws + 7340032;              // 16384 floats
    float* attn_out = ws + 7340032 + 16384;      // 16384*128 = 2,097,152 floats

    (void)in_sizes; (void)n_in; (void)out_size; (void)ws_size;

    gemm_qkvh<<<dim3(7, 256), 256, 0, stream>>>(x, qkv_w, qkv_b, g1_w, g1_b, qkvh);
    gate_kernel<<<4096, 256, 0, stream>>>(qkvh, g2_w, g2_b, gate);
    attn_kernel<<<PIXELS, 256, 0, stream>>>(qkvh, rpb, attn_out);
    gemm_proj<<<dim3(2, 256), 256, 0, stream>>>(attn_out, proj_w, proj_b, gate, x, out);
}

// Round 2
// 186.248 us; speedup vs baseline: 1.3737x; 1.3737x over previous
//
#include <hip/hip_runtime.h>
#include <hip/hip_bf16.h>
#include <math.h>

#define PIXELS 16384   // 4*64*64
#define C      128
#define KS     7
#define HEADS  4
#define HD     32      // head dim
#define QSCALE 0.17677669529663687f  // 32^-0.5

// ---------------------------------------------------------------------------
// Kernel 1: qkvh = x @ [qkv_w | g1_w] + [qkv_b | g1_b]; q cols scaled by QSCALE
// M=16384, K=128, N=448 (7 tiles of 64). grid=(7, 256), block=256.
// ---------------------------------------------------------------------------
__global__ __launch_bounds__(256) void gemm_qkvh(
    const float* __restrict__ x, const float* __restrict__ qkv_w,
    const float* __restrict__ qkv_b, const float* __restrict__ g1_w,
    const float* __restrict__ g1_b, float* __restrict__ qkvh)
{
    __shared__ float As[64 * 128];   // XOR-swizzled in f4 space
    __shared__ float Bs[128 * 64];
    const int nt = blockIdx.x;
    const int m0 = blockIdx.y * 64;
    const int tid = threadIdx.x;

#pragma unroll
    for (int it = 0; it < 8; it++) {
        int idx = tid + it * 256;          // 2048 f4 total
        int row = idx >> 5, c4 = idx & 31;
        float4 v = *(const float4*)(x + (size_t)(m0 + row) * 128 + c4 * 4);
        *(float4*)(As + row * 128 + ((c4 ^ (row & 7)) << 2)) = v;
    }
    if (nt < 6) {
#pragma unroll
        for (int it = 0; it < 8; it++) {
            int idx = tid + it * 256;
            int row = idx >> 4, c4 = idx & 15;
            *(float4*)(Bs + row * 64 + c4 * 4) =
                *(const float4*)(qkv_w + (size_t)row * 384 + nt * 64 + c4 * 4);
        }
    } else {
#pragma unroll
        for (int it = 0; it < 8; it++) {
            int idx = tid + it * 256;
            int row = idx >> 4, c4 = idx & 15;
            *(float4*)(Bs + row * 64 + c4 * 4) =
                *(const float4*)(g1_w + (size_t)row * 64 + c4 * 4);
        }
    }
    __syncthreads();

    const int ty = tid >> 4, tx = tid & 15;
    float acc[4][4] = {};
#pragma unroll 8
    for (int k4 = 0; k4 < 32; k4++) {
        float4 a[4], b[4];
#pragma unroll
        for (int mm = 0; mm < 4; mm++) {
            int m = ty * 4 + mm;
            a[mm] = *(const float4*)(As + m * 128 + ((k4 ^ (m & 7)) << 2));
        }
#pragma unroll
        for (int ii = 0; ii < 4; ii++)
            b[ii] = *(const float4*)(Bs + (k4 * 4 + ii) * 64 + tx * 4);
#pragma unroll
        for (int mm = 0; mm < 4; mm++) {
            float am[4] = {a[mm].x, a[mm].y, a[mm].z, a[mm].w};
#pragma unroll
            for (int ii = 0; ii < 4; ii++) {
                acc[mm][0] += am[ii] * b[ii].x;
                acc[mm][1] += am[ii] * b[ii].y;
                acc[mm][2] += am[ii] * b[ii].z;
                acc[mm][3] += am[ii] * b[ii].w;
            }
        }
    }

    const float qs = (nt < 2) ? QSCALE : 1.0f;
    float4 bias;
    if (nt < 6) bias = *(const float4*)(qkv_b + nt * 64 + tx * 4);
    else        bias = *(const float4*)(g1_b + tx * 4);
#pragma unroll
    for (int mm = 0; mm < 4; mm++) {
        int m = m0 + ty * 4 + mm;
        float4 o;
        o.x = (acc[mm][0] + bias.x) * qs;
        o.y = (acc[mm][1] + bias.y) * qs;
        o.z = (acc[mm][2] + bias.z) * qs;
        o.w = (acc[mm][3] + bias.w) * qs;
        *(float4*)(qkvh + (size_t)m * 448 + nt * 64 + tx * 4) = o;
    }
}

// ---------------------------------------------------------------------------
// Kernel 2: gate[p] = sigmoid(relu(hidden) . g2_w + g2_b). wave per pixel.
// ---------------------------------------------------------------------------
__global__ __launch_bounds__(256) void gate_kernel(
    const float* __restrict__ qkvh, const float* __restrict__ g2_w,
    const float* __restrict__ g2_b, float* __restrict__ gate)
{
    const int tid = threadIdx.x;
    const int lane = tid & 63;
    const int p = blockIdx.x * 4 + (tid >> 6);
    float h = qkvh[(size_t)p * 448 + 384 + lane];
    float v = fmaxf(h, 0.0f) * g2_w[lane];
#pragma unroll
    for (int off = 32; off >= 1; off >>= 1) v += __shfl_xor(v, off);
    if (lane == 0) {
        float g = v + g2_b[0];
        gate[p] = 1.0f / (1.0f + __expf(-g));
    }
}

// ---------------------------------------------------------------------------
// Kernel 3: neighborhood attention, tiled.
// Block = (batch b, 8x4 pixel tile, head h). Window union = fixed 14x10.
// LDS: kv[140][64] f32 (K f4 j=0..7 | V f4 j=8..15, XOR-swizzled),
//      q[32][32], rpb slice [169].  Total 40612 B -> 4 blocks/CU.
// grid = 4 batches * 128 tiles * 4 heads = 2048 blocks, 256 threads.
// ---------------------------------------------------------------------------
__global__ __launch_bounds__(256) void attn_kernel(
    const float* __restrict__ qkvh, const float* __restrict__ rpb,
    float* __restrict__ attn_out)
{
    __shared__ float kv[140 * 64];
    __shared__ float q_lds[32 * 32];
    __shared__ float rpb_lds[169];

    const int blk = blockIdx.x;
    const int h = blk & 3;
    const int tile = (blk >> 2) & 127;
    const int b = blk >> 9;
    const int tj0 = (tile & 15) * 4;      // 16 col tiles of 4
    const int ti0 = (tile >> 4) * 8;      // 8 row tiles of 8
    int wr0 = ti0 - 3; wr0 = wr0 < 0 ? 0 : (wr0 > 50 ? 50 : wr0);
    int wc0 = tj0 - 3; wc0 = wc0 < 0 ? 0 : (wc0 > 54 ? 54 : wc0);

    const int tid = threadIdx.x;

    if (tid < 169) rpb_lds[tid] = rpb[h * 169 + tid];

    {   // stage q: 32 pixels x 8 f4 (one f4 per thread)
        int pix = tid >> 3, jj = tid & 7;
        int pi = pix >> 2, pj = pix & 3;
        int gp = (b * 64 + ti0 + pi) * 64 + (tj0 + pj);
        float4 qv = *(const float4*)(qkvh + (size_t)gp * 448 + h * 32 + jj * 4);
        *(float4*)(q_lds + pix * 32 + jj * 4) = qv;
    }

    // stage KV: 140 positions x 16 f4.  j 0..7 = K head slice, 8..15 = V.
    for (int idx = tid; idx < 140 * 16; idx += 256) {
        int pos = idx >> 4, j = idx & 15;
        int rr = pos / 10, cc = pos - rr * 10;
        int gp = (b * 64 + wr0 + rr) * 64 + (wc0 + cc);
        int src = 128 + ((j >> 3) << 7) + h * 32 + ((j & 7) << 2);
        float4 v = *(const float4*)(qkvh + (size_t)gp * 448 + src);
        int js = (j & 8) | ((j & 7) ^ (pos & 7));   // XOR swizzle in f4 space
        *(float4*)(kv + pos * 64 + js * 4) = v;
    }
    __syncthreads();

    const int w = tid >> 6, lane = tid & 63;
    const int d4 = lane & 7, lg = lane >> 3;
    const int nr = (lane * 37) >> 8;        // lane/7 (valid lane<56)
    const int nc = lane - nr * 7;

#pragma unroll 1
    for (int s = 0; s < 8; s++) {
        const int pix = w * 8 + s;
        const int pi = pix >> 2, pj = pix & 3;
        const int i = ti0 + pi, jx = tj0 + pj;
        int sh = i - 3; sh = sh < 0 ? 0 : (sh > 57 ? 57 : sh);
        int sw = jx - 3; sw = sw < 0 ? 0 : (sw > 57 ? 57 : sw);
        const int dr = sh - wr0, dc = sw - wc0;

        // ---- scores: lane = neighbor (49 of 64 active) ----
        float sc = -INFINITY;
        if (lane < 49) {
            int pos = (dr + nr) * 10 + (dc + nc);
            int p7 = pos & 7;
            float acc = rpb_lds[(sh + nr - i + 6) * 13 + (sw + nc - jx + 6)];
            const float4* q4 = (const float4*)(q_lds + pix * 32);
#pragma unroll
            for (int jj = 0; jj < 8; jj++) {
                float4 qv = q4[jj];
                float4 kk = *(const float4*)(kv + pos * 64 + ((jj ^ p7) << 2));
                acc += qv.x * kk.x + qv.y * kk.y + qv.z * kk.z + qv.w * kk.w;
            }
            sc = acc;
        }
        // ---- wave softmax over 49 ----
        float m = sc;
#pragma unroll
        for (int off = 32; off >= 1; off >>= 1) m = fmaxf(m, __shfl_xor(m, off));
        float e = (lane < 49) ? __expf(sc - m) : 0.0f;
        float sum = e;
#pragma unroll
        for (int off = 32; off >= 1; off >>= 1) sum += __shfl_xor(sum, off);
        const float a = e / sum;   // lanes >=49 hold 0

        // ---- PV: lane = (lg in 0..7 over neighbors, d4 in 0..7 over dims) ----
        float4 acc4 = {0.f, 0.f, 0.f, 0.f};
#pragma unroll
        for (int t = 0; t < 7; t++) {
            int l = lg + 8 * t;
            float al = __shfl(a, l);        // 0 for l>=49
            int lr = (l * 37) >> 8, lc = l - lr * 7;
            int pos = (dr + lr) * 10 + (dc + lc);
            if (l >= 49) pos = 0;           // keep LDS read in-bounds; al==0
            int p7 = pos & 7;
            float4 vv = *(const float4*)(kv + pos * 64 + ((8 + (d4 ^ p7)) << 2));
            acc4.x += al * vv.x; acc4.y += al * vv.y;
            acc4.z += al * vv.z; acc4.w += al * vv.w;
        }
#pragma unroll
        for (int off = 8; off <= 32; off <<= 1) {
            acc4.x += __shfl_xor(acc4.x, off);
            acc4.y += __shfl_xor(acc4.y, off);
            acc4.z += __shfl_xor(acc4.z, off);
            acc4.w += __shfl_xor(acc4.w, off);
        }
        if (lg == 0) {
            int gp = (b * 64 + i) * 64 + jx;
            *(float4*)(attn_out + (size_t)gp * 128 + h * 32 + d4 * 4) = acc4;
        }
    }
}

// ---------------------------------------------------------------------------
// Kernel 4: out = (attn_out @ proj_w + proj_b) * gate + x
// ---------------------------------------------------------------------------
__global__ __launch_bounds__(256) void gemm_proj(
    const float* __restrict__ attn_in, const float* __restrict__ proj_w,
    const float* __restrict__ proj_b, const float* __restrict__ gate,
    const float* __restrict__ x, float* __restrict__ out)
{
    __shared__ float As[64 * 128];
    __shared__ float Bs[128 * 64];
    const int nt = blockIdx.x;
    const int m0 = blockIdx.y * 64;
    const int tid = threadIdx.x;

#pragma unroll
    for (int it = 0; it < 8; it++) {
        int idx = tid + it * 256;
        int row = idx >> 5, c4 = idx & 31;
        float4 v = *(const float4*)(attn_in + (size_t)(m0 + row) * 128 + c4 * 4);
        *(float4*)(As + row * 128 + ((c4 ^ (row & 7)) << 2)) = v;
    }
#pragma unroll
    for (int it = 0; it < 8; it++) {
        int idx = tid + it * 256;
        int row = idx >> 4, c4 = idx & 15;
        *(float4*)(Bs + row * 64 + c4 * 4) =
            *(const float4*)(proj_w + (size_t)row * 128 + nt * 64 + c4 * 4);
    }
    __syncthreads();

    const int ty = tid >> 4, tx = tid & 15;
    float acc[4][4] = {};
#pragma unroll 8
    for (int k4 = 0; k4 < 32; k4++) {
        float4 a[4], b[4];
#pragma unroll
        for (int mm = 0; mm < 4; mm++) {
            int m = ty * 4 + mm;
            a[mm] = *(const float4*)(As + m * 128 + ((k4 ^ (m & 7)) << 2));
        }
#pragma unroll
        for (int ii = 0; ii < 4; ii++)
            b[ii] = *(const float4*)(Bs + (k4 * 4 + ii) * 64 + tx * 4);
#pragma unroll
        for (int mm = 0; mm < 4; mm++) {
            float am[4] = {a[mm].x, a[mm].y, a[mm].z, a[mm].w};
#pragma unroll
            for (int ii = 0; ii < 4; ii++) {
                acc[mm][0] += am[ii] * b[ii].x;
                acc[mm][1] += am[ii] * b[ii].y;
                acc[mm][2] += am[ii] * b[ii].z;
                acc[mm][3] += am[ii] * b[ii].w;
            }
        }
    }

    float4 bias = *(const float4*)(proj_b + nt * 64 + tx * 4);
#pragma unroll
    for (int mm = 0; mm < 4; mm++) {
        int m = m0 + ty * 4 + mm;
        float gv = gate[m];
        float4 xv = *(const float4*)(x + (size_t)m * 128 + nt * 64 + tx * 4);
        float4 o;
        o.x = (acc[mm][0] + bias.x) * gv + xv.x;
        o.y = (acc[mm][1] + bias.y) * gv + xv.y;
        o.z = (acc[mm][2] + bias.z) * gv + xv.z;
        o.w = (acc[mm][3] + bias.w) * gv + xv.w;
        *(float4*)(out + (size_t)m * 128 + nt * 64 + tx * 4) = o;
    }
}

// ---------------------------------------------------------------------------
extern "C" void kernel_launch(void* const* d_in, const int* in_sizes, int n_in,
                              void* d_out, int out_size, void* d_ws, size_t ws_size,
                              hipStream_t stream)
{
    const float* x      = (const float*)d_in[0];
    const float* qkv_w  = (const float*)d_in[1];
    const float* qkv_b  = (const float*)d_in[2];
    const float* proj_w = (const float*)d_in[3];
    const float* proj_b = (const float*)d_in[4];
    const float* rpb    = (const float*)d_in[5];
    const float* g1_w   = (const float*)d_in[6];
    const float* g1_b   = (const float*)d_in[7];
    const float* g2_w   = (const float*)d_in[8];
    const float* g2_b   = (const float*)d_in[9];
    float* out = (float*)d_out;

    float* ws       = (float*)d_ws;
    float* qkvh     = ws;                        // 16384*448 floats
    float* gate     = ws + 7340032;              // 16384 floats
    float* attn_out = ws + 7340032 + 16384;      // 16384*128 floats

    (void)in_sizes; (void)n_in; (void)out_size; (void)ws_size;

    gemm_qkvh<<<dim3(7, 256), 256, 0, stream>>>(x, qkv_w, qkv_b, g1_w, g1_b, qkvh);
    gate_kernel<<<4096, 256, 0, stream>>>(qkvh, g2_w, g2_b, gate);
    attn_kernel<<<2048, 256, 0, stream>>>(qkvh, rpb, attn_out);
    gemm_proj<<<dim3(2, 256), 256, 0, stream>>>(attn_out, proj_w, proj_b, gate, x, out);
}

// Round 3
// 143.077 us; speedup vs baseline: 1.7882x; 1.3017x over previous
//
#include <hip/hip_runtime.h>
#include <hip/hip_bf16.h>
#include <math.h>

#define PIXELS 16384   // 4*64*64
#define C      128
#define KS     7
#define HEADS  4
#define HD     32      // head dim
#define QSCALE 0.17677669529663687f  // 32^-0.5

typedef __bf16 bf16x8 __attribute__((ext_vector_type(8)));
typedef float  f32x4  __attribute__((ext_vector_type(4)));

__device__ inline unsigned short f2bf(float f) {
    unsigned int u = __builtin_bit_cast(unsigned int, f);
    u += 0x7FFFu + ((u >> 16) & 1u);          // RNE
    return (unsigned short)(u >> 16);
}

// ---------------------------------------------------------------------------
// prep: x -> bf16 xb; wT[448][128] = [qkv_w|g1_w]^T bf16; pT[128][128] =
// proj_w^T bf16; bias_ext[448] = [qkv_b|g1_b].  grid 2121 x 256.
// ---------------------------------------------------------------------------
__global__ __launch_bounds__(256) void prep_kernel(
    const float* __restrict__ x, const float* __restrict__ qkv_w,
    const float* __restrict__ g1_w, const float* __restrict__ qkv_b,
    const float* __restrict__ g1_b, const float* __restrict__ proj_w,
    unsigned short* __restrict__ xb, unsigned short* __restrict__ wT,
    unsigned short* __restrict__ pT, float* __restrict__ bias_ext)
{
    const int blk = blockIdx.x, tid = threadIdx.x;
    if (blk < 2048) {
        int base = blk * 1024 + tid * 4;
        float4 v = *(const float4*)(x + base);
        ushort4 o; o.x = f2bf(v.x); o.y = f2bf(v.y); o.z = f2bf(v.z); o.w = f2bf(v.w);
        *(ushort4*)(xb + base) = o;
    } else if (blk < 2104) {
        int n = (blk - 2048) * 8 + (tid >> 5);
        int kq = tid & 31;
        float f0, f1, f2, f3;
        if (n < 384) {
            f0 = qkv_w[(kq*4+0)*384 + n]; f1 = qkv_w[(kq*4+1)*384 + n];
            f2 = qkv_w[(kq*4+2)*384 + n]; f3 = qkv_w[(kq*4+3)*384 + n];
        } else {
            int nn = n - 384;
            f0 = g1_w[(kq*4+0)*64 + nn]; f1 = g1_w[(kq*4+1)*64 + nn];
            f2 = g1_w[(kq*4+2)*64 + nn]; f3 = g1_w[(kq*4+3)*64 + nn];
        }
        ushort4 o; o.x = f2bf(f0); o.y = f2bf(f1); o.z = f2bf(f2); o.w = f2bf(f3);
        *(ushort4*)(wT + n*128 + kq*4) = o;
    } else if (blk < 2120) {
        int n = (blk - 2104) * 8 + (tid >> 5);
        int kq = tid & 31;
        ushort4 o;
        o.x = f2bf(proj_w[(kq*4+0)*128 + n]);
        o.y = f2bf(proj_w[(kq*4+1)*128 + n]);
        o.z = f2bf(proj_w[(kq*4+2)*128 + n]);
        o.w = f2bf(proj_w[(kq*4+3)*128 + n]);
        *(ushort4*)(pT + n*128 + kq*4) = o;
    } else {
        for (int idx = tid; idx < 448; idx += 256)
            bias_ext[idx] = (idx < 384) ? qkv_b[idx] : g1_b[idx - 384];
    }
}

// ---------------------------------------------------------------------------
// MFMA GEMM 1: qkvh = xb @ wT^T + bias (q cols scaled). BM=128 BN=64 K=128.
// grid (7, 128) x 256.  LDS 48 KB -> 3 blocks/CU.
// A/B staged bf16, chunk c of row r stored at f4 slot c^(r&7): frag reads and
// staging writes both land at the 8-row/bank-group b128 floor.
// ---------------------------------------------------------------------------
__global__ __launch_bounds__(256) void gemm_qkvh_mfma(
    const unsigned short* __restrict__ xb, const unsigned short* __restrict__ wT,
    const float* __restrict__ bias_ext, float* __restrict__ qkvh)
{
    __shared__ __align__(16) unsigned short As[128*128];
    __shared__ __align__(16) unsigned short Bs[64*128];
    const int n0 = blockIdx.x * 64;
    const int m0 = blockIdx.y * 128;
    const int tid = threadIdx.x;

#pragma unroll
    for (int it = 0; it < 8; it++) {
        int idx = tid + it*256, row = idx >> 4, c = idx & 15;
        uint4 v = *(const uint4*)(xb + (size_t)(m0+row)*128 + c*8);
        *(uint4*)(As + row*128 + ((c ^ (row&7)) << 3)) = v;
    }
#pragma unroll
    for (int it = 0; it < 4; it++) {
        int idx = tid + it*256, row = idx >> 4, c = idx & 15;
        uint4 v = *(const uint4*)(wT + (size_t)(n0+row)*128 + c*8);
        *(uint4*)(Bs + row*128 + ((c ^ (row&7)) << 3)) = v;
    }
    __syncthreads();

    const int wave = tid >> 6, lane = tid & 63;
    const int l15 = lane & 15, quad = lane >> 4;
    const int wm = (wave & 1) * 64, wn = (wave >> 1) * 32;

    f32x4 acc[4][2] = {};
#pragma unroll
    for (int ks = 0; ks < 4; ks++) {
        bf16x8 af[4], bq[2];
#pragma unroll
        for (int mt = 0; mt < 4; mt++) {
            int m = wm + mt*16 + l15;
            af[mt] = *(const bf16x8*)(As + m*128 + (((ks*4+quad) ^ (m&7)) << 3));
        }
#pragma unroll
        for (int nt = 0; nt < 2; nt++) {
            int n = wn + nt*16 + l15;
            bq[nt] = *(const bf16x8*)(Bs + n*128 + (((ks*4+quad) ^ (n&7)) << 3));
        }
#pragma unroll
        for (int mt = 0; mt < 4; mt++)
#pragma unroll
            for (int nt = 0; nt < 2; nt++)
                acc[mt][nt] = __builtin_amdgcn_mfma_f32_16x16x32_bf16(
                    af[mt], bq[nt], acc[mt][nt], 0, 0, 0);
    }

    // C/D layout: col = lane&15 (n), row = quad*4 + r (m)  [m89/m91 verified]
#pragma unroll
    for (int nt = 0; nt < 2; nt++) {
        int n = n0 + wn + nt*16 + l15;
        float qs = (n < 128) ? QSCALE : 1.0f;
        float bv = bias_ext[n];
#pragma unroll
        for (int mt = 0; mt < 4; mt++)
#pragma unroll
            for (int r = 0; r < 4; r++) {
                int m = m0 + wm + mt*16 + quad*4 + r;
                qkvh[(size_t)m*448 + n] = (acc[mt][nt][r] + bv) * qs;
            }
    }
}

// ---------------------------------------------------------------------------
// gate[p] = sigmoid(relu(hidden) . g2_w + g2_b). wave per pixel.
// ---------------------------------------------------------------------------
__global__ __launch_bounds__(256) void gate_kernel(
    const float* __restrict__ qkvh, const float* __restrict__ g2_w,
    const float* __restrict__ g2_b, float* __restrict__ gate)
{
    const int tid = threadIdx.x;
    const int lane = tid & 63;
    const int p = blockIdx.x * 4 + (tid >> 6);
    float h = qkvh[(size_t)p * 448 + 384 + lane];
    float v = fmaxf(h, 0.0f) * g2_w[lane];
#pragma unroll
    for (int off = 32; off >= 1; off >>= 1) v += __shfl_xor(v, off);
    if (lane == 0) {
        float g = v + g2_b[0];
        gate[p] = 1.0f / (1.0f + __expf(-g));
    }
}

// ---------------------------------------------------------------------------
// attention (tiled, as round 2) — max-free softmax (scores bounded ~1),
// bf16 output for the MFMA proj GEMM.
// ---------------------------------------------------------------------------
__global__ __launch_bounds__(256) void attn_kernel(
    const float* __restrict__ qkvh, const float* __restrict__ rpb,
    unsigned short* __restrict__ attnb)
{
    __shared__ float kv[140 * 64];
    __shared__ float q_lds[32 * 32];
    __shared__ float rpb_lds[169];

    const int blk = blockIdx.x;
    const int h = blk & 3;
    const int tile = (blk >> 2) & 127;
    const int b = blk >> 9;
    const int tj0 = (tile & 15) * 4;
    const int ti0 = (tile >> 4) * 8;
    int wr0 = ti0 - 3; wr0 = wr0 < 0 ? 0 : (wr0 > 50 ? 50 : wr0);
    int wc0 = tj0 - 3; wc0 = wc0 < 0 ? 0 : (wc0 > 54 ? 54 : wc0);

    const int tid = threadIdx.x;

    if (tid < 169) rpb_lds[tid] = rpb[h * 169 + tid];

    {   // stage q: 32 pixels x 8 f4
        int pix = tid >> 3, jj = tid & 7;
        int pi = pix >> 2, pj = pix & 3;
        int gp = (b * 64 + ti0 + pi) * 64 + (tj0 + pj);
        float4 qv = *(const float4*)(qkvh + (size_t)gp * 448 + h * 32 + jj * 4);
        *(float4*)(q_lds + pix * 32 + jj * 4) = qv;
    }
    // stage KV: 140 positions x 16 f4 (K | V head slices), XOR swizzled
    for (int idx = tid; idx < 140 * 16; idx += 256) {
        int pos = idx >> 4, j = idx & 15;
        int rr = pos / 10, cc = pos - rr * 10;
        int gp = (b * 64 + wr0 + rr) * 64 + (wc0 + cc);
        int src = 128 + ((j >> 3) << 7) + h * 32 + ((j & 7) << 2);
        float4 v = *(const float4*)(qkvh + (size_t)gp * 448 + src);
        int js = (j & 8) | ((j & 7) ^ (pos & 7));
        *(float4*)(kv + pos * 64 + js * 4) = v;
    }
    __syncthreads();

    const int w = tid >> 6, lane = tid & 63;
    const int d4 = lane & 7, lg = lane >> 3;
    const int nr = (lane * 37) >> 8;
    const int nc = lane - nr * 7;

#pragma unroll 1
    for (int s = 0; s < 8; s++) {
        const int pix = w * 8 + s;
        const int pi = pix >> 2, pj = pix & 3;
        const int i = ti0 + pi, jx = tj0 + pj;
        int sh = i - 3; sh = sh < 0 ? 0 : (sh > 57 ? 57 : sh);
        int sw = jx - 3; sw = sw < 0 ? 0 : (sw > 57 ? 57 : sw);
        const int dr = sh - wr0, dc = sw - wc0;

        float e = 0.0f;
        if (lane < 49) {
            int pos = (dr + nr) * 10 + (dc + nc);
            int p7 = pos & 7;
            float acc = rpb_lds[(sh + nr - i + 6) * 13 + (sw + nc - jx + 6)];
            const float4* q4 = (const float4*)(q_lds + pix * 32);
#pragma unroll
            for (int jj = 0; jj < 8; jj++) {
                float4 qv = q4[jj];
                float4 kk = *(const float4*)(kv + pos * 64 + ((jj ^ p7) << 2));
                acc += qv.x * kk.x + qv.y * kk.y + qv.z * kk.z + qv.w * kk.w;
            }
            e = __expf(acc);   // scores bounded (|s| ~ 0.3): max-free softmax
        }
        float sum = e;
#pragma unroll
        for (int off = 32; off >= 1; off >>= 1) sum += __shfl_xor(sum, off);
        const float a = e / sum;

        float4 acc4 = {0.f, 0.f, 0.f, 0.f};
#pragma unroll
        for (int t = 0; t < 7; t++) {
            int l = lg + 8 * t;
            float al = __shfl(a, l);
            int lr = (l * 37) >> 8, lc = l - lr * 7;
            int pos = (dr + lr) * 10 + (dc + lc);
            if (l >= 49) pos = 0;
            int p7 = pos & 7;
            float4 vv = *(const float4*)(kv + pos * 64 + ((8 + (d4 ^ p7)) << 2));
            acc4.x += al * vv.x; acc4.y += al * vv.y;
            acc4.z += al * vv.z; acc4.w += al * vv.w;
        }
#pragma unroll
        for (int off = 8; off <= 32; off <<= 1) {
            acc4.x += __shfl_xor(acc4.x, off);
            acc4.y += __shfl_xor(acc4.y, off);
            acc4.z += __shfl_xor(acc4.z, off);
            acc4.w += __shfl_xor(acc4.w, off);
        }
        if (lg == 0) {
            int gp = (b * 64 + i) * 64 + jx;
            ushort4 o;
            o.x = f2bf(acc4.x); o.y = f2bf(acc4.y);
            o.z = f2bf(acc4.z); o.w = f2bf(acc4.w);
            *(ushort4*)(attnb + (size_t)gp * 128 + h * 32 + d4 * 4) = o;
        }
    }
}

// ---------------------------------------------------------------------------
// MFMA GEMM 2: out = (attnb @ pT^T + proj_b) * gate + x. BM=64 BN=64 K=128.
// grid (2, 256) x 256.  LDS 32 KB.
// ---------------------------------------------------------------------------
__global__ __launch_bounds__(256) void gemm_proj_mfma(
    const unsigned short* __restrict__ ab, const unsigned short* __restrict__ pT,
    const float* __restrict__ proj_b, const float* __restrict__ gate,
    const float* __restrict__ x, float* __restrict__ out)
{
    __shared__ __align__(16) unsigned short As[64*128];
    __shared__ __align__(16) unsigned short Bs[64*128];
    const int n0 = blockIdx.x * 64;
    const int m0 = blockIdx.y * 64;
    const int tid = threadIdx.x;

#pragma unroll
    for (int it = 0; it < 4; it++) {
        int idx = tid + it*256, row = idx >> 4, c = idx & 15;
        uint4 v = *(const uint4*)(ab + (size_t)(m0+row)*128 + c*8);
        *(uint4*)(As + row*128 + ((c ^ (row&7)) << 3)) = v;
    }
#pragma unroll
    for (int it = 0; it < 4; it++) {
        int idx = tid + it*256, row = idx >> 4, c = idx & 15;
        uint4 v = *(const uint4*)(pT + (size_t)(n0+row)*128 + c*8);
        *(uint4*)(Bs + row*128 + ((c ^ (row&7)) << 3)) = v;
    }
    __syncthreads();

    const int wave = tid >> 6, lane = tid & 63;
    const int l15 = lane & 15, quad = lane >> 4;
    const int wm = (wave & 1) * 32, wn = (wave >> 1) * 32;

    f32x4 acc[2][2] = {};
#pragma unroll
    for (int ks = 0; ks < 4; ks++) {
        bf16x8 af[2], bq[2];
#pragma unroll
        for (int mt = 0; mt < 2; mt++) {
            int m = wm + mt*16 + l15;
            af[mt] = *(const bf16x8*)(As + m*128 + (((ks*4+quad) ^ (m&7)) << 3));
        }
#pragma unroll
        for (int nt = 0; nt < 2; nt++) {
            int n = wn + nt*16 + l15;
            bq[nt] = *(const bf16x8*)(Bs + n*128 + (((ks*4+quad) ^ (n&7)) << 3));
        }
#pragma unroll
        for (int mt = 0; mt < 2; mt++)
#pragma unroll
            for (int nt = 0; nt < 2; nt++)
                acc[mt][nt] = __builtin_amdgcn_mfma_f32_16x16x32_bf16(
                    af[mt], bq[nt], acc[mt][nt], 0, 0, 0);
    }

#pragma unroll
    for (int nt = 0; nt < 2; nt++) {
        int n = n0 + wn + nt*16 + l15;
        float bv = proj_b[n];
#pragma unroll
        for (int mt = 0; mt < 2; mt++)
#pragma unroll
            for (int r = 0; r < 4; r++) {
                int m = m0 + wm + mt*16 + quad*4 + r;
                out[(size_t)m*128 + n] =
                    (acc[mt][nt][r] + bv) * gate[m] + x[(size_t)m*128 + n];
            }
    }
}

// ---------------------------------------------------------------------------
extern "C" void kernel_launch(void* const* d_in, const int* in_sizes, int n_in,
                              void* d_out, int out_size, void* d_ws, size_t ws_size,
                              hipStream_t stream)
{
    const float* x      = (const float*)d_in[0];
    const float* qkv_w  = (const float*)d_in[1];
    const float* qkv_b  = (const float*)d_in[2];
    const float* proj_w = (const float*)d_in[3];
    const float* proj_b = (const float*)d_in[4];
    const float* rpb    = (const float*)d_in[5];
    const float* g1_w   = (const float*)d_in[6];
    const float* g1_b   = (const float*)d_in[7];
    const float* g2_w   = (const float*)d_in[8];
    const float* g2_b   = (const float*)d_in[9];
    float* out = (float*)d_out;

    float* ws        = (float*)d_ws;
    float* qkvh      = ws;                         // 16384*448 f32
    float* gate      = ws + 7340032;               // 16384 f32
    float* bias_ext  = gate + 16384;               // 448 f32
    unsigned short* xb    = (unsigned short*)(bias_ext + 448);  // 16384*128 bf16
    unsigned short* wT    = xb + 2097152;          // 448*128 bf16
    unsigned short* pT    = wT + 57344;            // 128*128 bf16
    unsigned short* attnb = pT + 16384;            // 16384*128 bf16

    (void)in_sizes; (void)n_in; (void)out_size; (void)ws_size;

    prep_kernel<<<2121, 256, 0, stream>>>(x, qkv_w, g1_w, qkv_b, g1_b, proj_w,
                                          xb, wT, pT, bias_ext);
    gemm_qkvh_mfma<<<dim3(7, 128), 256, 0, stream>>>(xb, wT, bias_ext, qkvh);
    gate_kernel<<<4096, 256, 0, stream>>>(qkvh, g2_w, g2_b, gate);
    attn_kernel<<<2048, 256, 0, stream>>>(qkvh, rpb, attnb);
    gemm_proj_mfma<<<dim3(2, 256), 256, 0, stream>>>(attnb, pT, proj_b, gate, x, out);
}

// Round 4
// 134.858 us; speedup vs baseline: 1.8972x; 1.0610x over previous
//
#include <hip/hip_runtime.h>
#include <hip/hip_bf16.h>
#include <math.h>

#define PIXELS 16384   // 4*64*64
#define C      128
#define KS     7
#define HEADS  4
#define HD     32      // head dim
#define QSCALE 0.17677669529663687f  // 32^-0.5

typedef __bf16 bf16x8 __attribute__((ext_vector_type(8)));
typedef float  f32x4  __attribute__((ext_vector_type(4)));

__device__ inline unsigned short f2bf(float f) {
    unsigned int u = __builtin_bit_cast(unsigned int, f);
    u += 0x7FFFu + ((u >> 16) & 1u);          // RNE
    return (unsigned short)(u >> 16);
}
__device__ inline float bflo(unsigned int u) {
    return __builtin_bit_cast(float, u << 16);
}
__device__ inline float bfhi(unsigned int u) {
    return __builtin_bit_cast(float, u & 0xFFFF0000u);
}

// ---------------------------------------------------------------------------
// prep: x -> bf16 xb; wT[448][128] = [qkv_w|g1_w]^T bf16; pT[128][128] =
// proj_w^T bf16; bias_ext[448] = [qkv_b|g1_b].  grid 2121 x 256.
// ---------------------------------------------------------------------------
__global__ __launch_bounds__(256) void prep_kernel(
    const float* __restrict__ x, const float* __restrict__ qkv_w,
    const float* __restrict__ g1_w, const float* __restrict__ qkv_b,
    const float* __restrict__ g1_b, const float* __restrict__ proj_w,
    unsigned short* __restrict__ xb, unsigned short* __restrict__ wT,
    unsigned short* __restrict__ pT, float* __restrict__ bias_ext)
{
    const int blk = blockIdx.x, tid = threadIdx.x;
    if (blk < 2048) {
        int base = blk * 1024 + tid * 4;
        float4 v = *(const float4*)(x + base);
        ushort4 o; o.x = f2bf(v.x); o.y = f2bf(v.y); o.z = f2bf(v.z); o.w = f2bf(v.w);
        *(ushort4*)(xb + base) = o;
    } else if (blk < 2104) {
        int n = (blk - 2048) * 8 + (tid >> 5);
        int kq = tid & 31;
        float f0, f1, f2, f3;
        if (n < 384) {
            f0 = qkv_w[(kq*4+0)*384 + n]; f1 = qkv_w[(kq*4+1)*384 + n];
            f2 = qkv_w[(kq*4+2)*384 + n]; f3 = qkv_w[(kq*4+3)*384 + n];
        } else {
            int nn = n - 384;
            f0 = g1_w[(kq*4+0)*64 + nn]; f1 = g1_w[(kq*4+1)*64 + nn];
            f2 = g1_w[(kq*4+2)*64 + nn]; f3 = g1_w[(kq*4+3)*64 + nn];
        }
        ushort4 o; o.x = f2bf(f0); o.y = f2bf(f1); o.z = f2bf(f2); o.w = f2bf(f3);
        *(ushort4*)(wT + n*128 + kq*4) = o;
    } else if (blk < 2120) {
        int n = (blk - 2104) * 8 + (tid >> 5);
        int kq = tid & 31;
        ushort4 o;
        o.x = f2bf(proj_w[(kq*4+0)*128 + n]);
        o.y = f2bf(proj_w[(kq*4+1)*128 + n]);
        o.z = f2bf(proj_w[(kq*4+2)*128 + n]);
        o.w = f2bf(proj_w[(kq*4+3)*128 + n]);
        *(ushort4*)(pT + n*128 + kq*4) = o;
    } else {
        for (int idx = tid; idx < 448; idx += 256)
            bias_ext[idx] = (idx < 384) ? qkv_b[idx] : g1_b[idx - 384];
    }
}

// ---------------------------------------------------------------------------
// GEMM 1 (fused): qkvb[pix][384] bf16 = bf16(x @ W + b), q cols scaled.
// nt==6 block computes gate[m] = sigmoid(sum relu(h)*g2w + g2b) instead of
// storing.  BM=64 BN=64 K=128, grid (7, 256) x 256, LDS 32 KB -> 5 blk/CU.
// ---------------------------------------------------------------------------
__global__ __launch_bounds__(256) void gemm_qkvh_fused(
    const unsigned short* __restrict__ xb, const unsigned short* __restrict__ wT,
    const float* __restrict__ bias_ext, const float* __restrict__ g2_w,
    const float* __restrict__ g2_b, unsigned short* __restrict__ qkvb,
    float* __restrict__ gate)
{
    __shared__ __align__(16) unsigned short As[64*128];
    __shared__ __align__(16) unsigned short Bs[64*128];
    const int nt = blockIdx.x;
    const int n0 = nt * 64;
    const int m0 = blockIdx.y * 64;
    const int tid = threadIdx.x;

#pragma unroll
    for (int it = 0; it < 4; it++) {
        int idx = tid + it*256, row = idx >> 4, c = idx & 15;
        uint4 v = *(const uint4*)(xb + (size_t)(m0+row)*128 + c*8);
        *(uint4*)(As + row*128 + ((c ^ (row&7)) << 3)) = v;
    }
#pragma unroll
    for (int it = 0; it < 4; it++) {
        int idx = tid + it*256, row = idx >> 4, c = idx & 15;
        uint4 v = *(const uint4*)(wT + (size_t)(n0+row)*128 + c*8);
        *(uint4*)(Bs + row*128 + ((c ^ (row&7)) << 3)) = v;
    }
    __syncthreads();

    const int wave = tid >> 6, lane = tid & 63;
    const int l15 = lane & 15, quad = lane >> 4;
    const int wm = (wave & 1) * 32, wn = (wave >> 1) * 32;

    f32x4 acc[2][2] = {};
#pragma unroll
    for (int ks = 0; ks < 4; ks++) {
        bf16x8 af[2], bq[2];
#pragma unroll
        for (int mt = 0; mt < 2; mt++) {
            int m = wm + mt*16 + l15;
            af[mt] = *(const bf16x8*)(As + m*128 + (((ks*4+quad) ^ (m&7)) << 3));
        }
#pragma unroll
        for (int ntl = 0; ntl < 2; ntl++) {
            int n = wn + ntl*16 + l15;
            bq[ntl] = *(const bf16x8*)(Bs + n*128 + (((ks*4+quad) ^ (n&7)) << 3));
        }
#pragma unroll
        for (int mt = 0; mt < 2; mt++)
#pragma unroll
            for (int ntl = 0; ntl < 2; ntl++)
                acc[mt][ntl] = __builtin_amdgcn_mfma_f32_16x16x32_bf16(
                    af[mt], bq[ntl], acc[mt][ntl], 0, 0, 0);
    }
    __syncthreads();   // As/Bs dead; reuse below

    if (nt < 6) {
        // C layout: col=lane&15 (n), row=quad*4+r (m).  Roundtrip via LDS for
        // coalesced bf16 stores.
        unsigned short* Cs = (unsigned short*)As;   // 64x64 bf16 = 8 KB
#pragma unroll
        for (int ntl = 0; ntl < 2; ntl++) {
            int nl = wn + ntl*16 + l15;
            int ng = n0 + nl;
            float qs = (ng < 128) ? QSCALE : 1.0f;
            float bv = bias_ext[ng];
#pragma unroll
            for (int mt = 0; mt < 2; mt++)
#pragma unroll
                for (int r = 0; r < 4; r++) {
                    int ml = wm + mt*16 + quad*4 + r;
                    Cs[ml*64 + nl] = f2bf((acc[mt][ntl][r] + bv) * qs);
                }
        }
        __syncthreads();
        int row = tid >> 2, part = tid & 3;
        uint4 a = *(const uint4*)(Cs + row*64 + part*16);
        uint4 b = *(const uint4*)(Cs + row*64 + part*16 + 8);
        unsigned short* dst = qkvb + (size_t)(m0+row)*384 + n0 + part*16;
        *(uint4*)dst = a;
        *(uint4*)(dst + 8) = b;
    } else {
        // gate: sum over 64 hidden cols of relu(h)*g2w, sigmoid.
        float* gpart = (float*)Bs;   // [2][64]
        float rs[2][4];
#pragma unroll
        for (int mt = 0; mt < 2; mt++)
#pragma unroll
            for (int r = 0; r < 4; r++) rs[mt][r] = 0.0f;
#pragma unroll
        for (int ntl = 0; ntl < 2; ntl++) {
            int nl = wn + ntl*16 + l15;
            float bv = bias_ext[384 + nl];
            float gw = g2_w[nl];
#pragma unroll
            for (int mt = 0; mt < 2; mt++)
#pragma unroll
                for (int r = 0; r < 4; r++) {
                    float h = acc[mt][ntl][r] + bv;
                    rs[mt][r] += fmaxf(h, 0.0f) * gw;
                }
        }
#pragma unroll
        for (int off = 1; off <= 8; off <<= 1)
#pragma unroll
            for (int mt = 0; mt < 2; mt++)
#pragma unroll
                for (int r = 0; r < 4; r++)
                    rs[mt][r] += __shfl_xor(rs[mt][r], off);
        if (l15 == 0) {
#pragma unroll
            for (int mt = 0; mt < 2; mt++)
#pragma unroll
                for (int r = 0; r < 4; r++)
                    gpart[(wave >> 1)*64 + wm + mt*16 + quad*4 + r] = rs[mt][r];
        }
        __syncthreads();
        if (tid < 64) {
            float g = gpart[tid] + gpart[64 + tid] + g2_b[0];
            gate[m0 + tid] = 1.0f / (1.0f + __expf(-g));
        }
    }
}

// ---------------------------------------------------------------------------
// attention: bf16 K/V in LDS (unpack on read), fp32 q pre-unpacked.
// LDS ~22.7 KB -> 7 blocks/CU.  grid 2048 x 256.
// kvs[pos][8 chunks of 8 bf16], chunk c stored at slot c^(pos&7).
// chunks 0..3 = K dims, 4..7 = V dims (head slice).
// ---------------------------------------------------------------------------
__global__ __launch_bounds__(256) void attn_kernel(
    const unsigned short* __restrict__ qkvb, const float* __restrict__ rpb,
    unsigned short* __restrict__ attnb)
{
    __shared__ __align__(16) unsigned short kvs[140 * 64];  // 17.5 KB
    __shared__ float qf[32 * 32];                           // 4 KB
    __shared__ float rpb_lds[169];

    const int blk = blockIdx.x;
    const int h = blk & 3;
    const int tile = (blk >> 2) & 127;
    const int b = blk >> 9;
    const int tj0 = (tile & 15) * 4;
    const int ti0 = (tile >> 4) * 8;
    int wr0 = ti0 - 3; wr0 = wr0 < 0 ? 0 : (wr0 > 50 ? 50 : wr0);
    int wc0 = tj0 - 3; wc0 = wc0 < 0 ? 0 : (wc0 > 54 ? 54 : wc0);

    const int tid = threadIdx.x;

    if (tid < 169) rpb_lds[tid] = rpb[h * 169 + tid];

    if (tid < 128) {   // q: 32 pix x 4 chunks, unpack to fp32
        int pix = tid >> 2, jj = tid & 3;
        int pi = pix >> 2, pj = pix & 3;
        int gp = (b * 64 + ti0 + pi) * 64 + (tj0 + pj);
        uint4 u = *(const uint4*)(qkvb + (size_t)gp * 384 + h * 32 + jj * 8);
        float4 qa = { bflo(u.x), bfhi(u.x), bflo(u.y), bfhi(u.y) };
        float4 qb = { bflo(u.z), bfhi(u.z), bflo(u.w), bfhi(u.w) };
        *(float4*)(qf + pix*32 + jj*8)     = qa;
        *(float4*)(qf + pix*32 + jj*8 + 4) = qb;
    }
    // KV: 140 pos x 8 chunks (16B each)
    for (int idx = tid; idx < 140 * 8; idx += 256) {
        int pos = idx >> 3, c = idx & 7;
        int rr = pos / 10, cc = pos - rr * 10;
        int gp = (b * 64 + wr0 + rr) * 64 + (wc0 + cc);
        int off = 128 + ((c >> 2) << 7) + h * 32 + ((c & 3) << 3);
        uint4 v = *(const uint4*)(qkvb + (size_t)gp * 384 + off);
        *(uint4*)(kvs + pos*64 + ((c ^ (pos & 7)) << 3)) = v;
    }
    __syncthreads();

    const int w = tid >> 6, lane = tid & 63;
    const int d4 = lane & 7, lg = lane >> 3;
    const int nr = (lane * 37) >> 8;
    const int nc = lane - nr * 7;

#pragma unroll 1
    for (int s = 0; s < 8; s++) {
        const int pix = w * 8 + s;
        const int pi = pix >> 2, pj = pix & 3;
        const int i = ti0 + pi, jx = tj0 + pj;
        int sh = i - 3; sh = sh < 0 ? 0 : (sh > 57 ? 57 : sh);
        int sw = jx - 3; sw = sw < 0 ? 0 : (sw > 57 ? 57 : sw);
        const int dr = sh - wr0, dc = sw - wc0;

        float e = 0.0f;
        if (lane < 49) {
            int pos = (dr + nr) * 10 + (dc + nc);
            int p7 = pos & 7;
            float acc = rpb_lds[(sh + nr - i + 6) * 13 + (sw + nc - jx + 6)];
            const float4* q4 = (const float4*)(qf + pix * 32);
#pragma unroll
            for (int c = 0; c < 4; c++) {
                uint4 k = *(const uint4*)(kvs + pos*64 + ((c ^ p7) << 3));
                float4 qa = q4[c*2], qb = q4[c*2+1];
                acc += qa.x*bflo(k.x) + qa.y*bfhi(k.x)
                     + qa.z*bflo(k.y) + qa.w*bfhi(k.y)
                     + qb.x*bflo(k.z) + qb.y*bfhi(k.z)
                     + qb.z*bflo(k.w) + qb.w*bfhi(k.w);
            }
            e = __expf(acc);   // max-free: scores bounded
        }
        float sum = e;
#pragma unroll
        for (int off = 32; off >= 1; off >>= 1) sum += __shfl_xor(sum, off);
        const float a = e / sum;

        float4 acc4 = {0.f, 0.f, 0.f, 0.f};
#pragma unroll
        for (int t = 0; t < 7; t++) {
            int l = lg + 8 * t;
            float al = __shfl(a, l);
            int lr = (l * 37) >> 8, lc = l - lr * 7;
            int pos = (dr + lr) * 10 + (dc + lc);
            if (l >= 49) pos = 0;
            int p7 = pos & 7;
            uint2 v2 = *(const uint2*)(kvs + pos*64 +
                           (((4 + (d4 >> 1)) ^ p7) << 3) + ((d4 & 1) << 2));
            acc4.x += al * bflo(v2.x); acc4.y += al * bfhi(v2.x);
            acc4.z += al * bflo(v2.y); acc4.w += al * bfhi(v2.y);
        }
#pragma unroll
        for (int off = 8; off <= 32; off <<= 1) {
            acc4.x += __shfl_xor(acc4.x, off);
            acc4.y += __shfl_xor(acc4.y, off);
            acc4.z += __shfl_xor(acc4.z, off);
            acc4.w += __shfl_xor(acc4.w, off);
        }
        if (lg == 0) {
            int gp = (b * 64 + i) * 64 + jx;
            ushort4 o;
            o.x = f2bf(acc4.x); o.y = f2bf(acc4.y);
            o.z = f2bf(acc4.z); o.w = f2bf(acc4.w);
            *(ushort4*)(attnb + (size_t)gp * 128 + h * 32 + d4 * 4) = o;
        }
    }
}

// ---------------------------------------------------------------------------
// GEMM 2: out = (attnb @ pT^T + proj_b) * gate + x.  BM=64 BN=64 K=128.
// LDS-roundtrip epilogue for coalesced fp32 stores. grid (2, 256) x 256.
// ---------------------------------------------------------------------------
__global__ __launch_bounds__(256) void gemm_proj_mfma(
    const unsigned short* __restrict__ ab, const unsigned short* __restrict__ pT,
    const float* __restrict__ proj_b, const float* __restrict__ gate,
    const float* __restrict__ x, float* __restrict__ out)
{
    __shared__ __align__(16) unsigned short As[64*128];
    __shared__ __align__(16) unsigned short Bs[64*128];
    const int n0 = blockIdx.x * 64;
    const int m0 = blockIdx.y * 64;
    const int tid = threadIdx.x;

#pragma unroll
    for (int it = 0; it < 4; it++) {
        int idx = tid + it*256, row = idx >> 4, c = idx & 15;
        uint4 v = *(const uint4*)(ab + (size_t)(m0+row)*128 + c*8);
        *(uint4*)(As + row*128 + ((c ^ (row&7)) << 3)) = v;
    }
#pragma unroll
    for (int it = 0; it < 4; it++) {
        int idx = tid + it*256, row = idx >> 4, c = idx & 15;
        uint4 v = *(const uint4*)(pT + (size_t)(n0+row)*128 + c*8);
        *(uint4*)(Bs + row*128 + ((c ^ (row&7)) << 3)) = v;
    }
    __syncthreads();

    const int wave = tid >> 6, lane = tid & 63;
    const int l15 = lane & 15, quad = lane >> 4;
    const int wm = (wave & 1) * 32, wn = (wave >> 1) * 32;

    f32x4 acc[2][2] = {};
#pragma unroll
    for (int ks = 0; ks < 4; ks++) {
        bf16x8 af[2], bq[2];
#pragma unroll
        for (int mt = 0; mt < 2; mt++) {
            int m = wm + mt*16 + l15;
            af[mt] = *(const bf16x8*)(As + m*128 + (((ks*4+quad) ^ (m&7)) << 3));
        }
#pragma unroll
        for (int ntl = 0; ntl < 2; ntl++) {
            int n = wn + ntl*16 + l15;
            bq[ntl] = *(const bf16x8*)(Bs + n*128 + (((ks*4+quad) ^ (n&7)) << 3));
        }
#pragma unroll
        for (int mt = 0; mt < 2; mt++)
#pragma unroll
            for (int ntl = 0; ntl < 2; ntl++)
                acc[mt][ntl] = __builtin_amdgcn_mfma_f32_16x16x32_bf16(
                    af[mt], bq[ntl], acc[mt][ntl], 0, 0, 0);
    }
    __syncthreads();

    float* Cs = (float*)As;   // 64x64 f32 = 16 KB
#pragma unroll
    for (int ntl = 0; ntl < 2; ntl++) {
        int nl = wn + ntl*16 + l15;
        float bv = proj_b[n0 + nl];
#pragma unroll
        for (int mt = 0; mt < 2; mt++)
#pragma unroll
            for (int r = 0; r < 4; r++) {
                int ml = wm + mt*16 + quad*4 + r;
                Cs[ml*64 + nl] = acc[mt][ntl][r] + bv;
            }
    }
    __syncthreads();
    int row = tid >> 2, part = tid & 3;
    float gv = gate[m0 + row];
    const float* xr = x + (size_t)(m0+row)*128 + n0 + part*16;
    float* orow = out + (size_t)(m0+row)*128 + n0 + part*16;
#pragma unroll
    for (int q = 0; q < 4; q++) {
        float4 cv = *(const float4*)(Cs + row*64 + part*16 + q*4);
        float4 xv = *(const float4*)(xr + q*4);
        float4 o;
        o.x = cv.x * gv + xv.x; o.y = cv.y * gv + xv.y;
        o.z = cv.z * gv + xv.z; o.w = cv.w * gv + xv.w;
        *(float4*)(orow + q*4) = o;
    }
}

// ---------------------------------------------------------------------------
extern "C" void kernel_launch(void* const* d_in, const int* in_sizes, int n_in,
                              void* d_out, int out_size, void* d_ws, size_t ws_size,
                              hipStream_t stream)
{
    const float* x      = (const float*)d_in[0];
    const float* qkv_w  = (const float*)d_in[1];
    const float* qkv_b  = (const float*)d_in[2];
    const float* proj_w = (const float*)d_in[3];
    const float* proj_b = (const float*)d_in[4];
    const float* rpb    = (const float*)d_in[5];
    const float* g1_w   = (const float*)d_in[6];
    const float* g1_b   = (const float*)d_in[7];
    const float* g2_w   = (const float*)d_in[8];
    const float* g2_b   = (const float*)d_in[9];
    float* out = (float*)d_out;

    float* ws        = (float*)d_ws;
    float* gate      = ws;                          // 16384 f32
    float* bias_ext  = gate + 16384;                // 448 f32
    unsigned short* xb    = (unsigned short*)(bias_ext + 448);  // 16384*128
    unsigned short* wT    = xb + 2097152;           // 448*128
    unsigned short* pT    = wT + 57344;             // 128*128
    unsigned short* qkvb  = pT + 16384;             // 16384*384 bf16
    unsigned short* attnb = qkvb + 6291456;         // 16384*128 bf16

    (void)in_sizes; (void)n_in; (void)out_size; (void)ws_size;

    prep_kernel<<<2121, 256, 0, stream>>>(x, qkv_w, g1_w, qkv_b, g1_b, proj_w,
                                          xb, wT, pT, bias_ext);
    gemm_qkvh_fused<<<dim3(7, 256), 256, 0, stream>>>(xb, wT, bias_ext,
                                                      g2_w, g2_b, qkvb, gate);
    attn_kernel<<<2048, 256, 0, stream>>>(qkvb, rpb, attnb);
    gemm_proj_mfma<<<dim3(2, 256), 256, 0, stream>>>(attnb, pT, proj_b, gate, x, out);
}

// Round 5
// 125.063 us; speedup vs baseline: 2.0458x; 1.0783x over previous
//
#include <hip/hip_runtime.h>
#include <hip/hip_bf16.h>
#include <math.h>

#define PIXELS 16384   // 4*64*64
#define C      128
#define KS     7
#define HEADS  4
#define HD     32      // head dim
#define QSCALE 0.17677669529663687f  // 32^-0.5

typedef __bf16 bf16x8 __attribute__((ext_vector_type(8)));
typedef float  f32x4  __attribute__((ext_vector_type(4)));

__device__ inline unsigned short f2bf(float f) {
    unsigned int u = __builtin_bit_cast(unsigned int, f);
    u += 0x7FFFu + ((u >> 16) & 1u);          // RNE
    return (unsigned short)(u >> 16);
}
__device__ inline float bflo(unsigned int u) {
    return __builtin_bit_cast(float, u << 16);
}
__device__ inline float bfhi(unsigned int u) {
    return __builtin_bit_cast(float, u & 0xFFFF0000u);
}

// ---------------------------------------------------------------------------
// prep: x -> bf16 xb; wT[448][128] = [qkv_w|g1_w]^T bf16; pT[128][128] =
// proj_w^T bf16; bias_ext[448] = [qkv_b|g1_b].  grid 2121 x 256.
// ---------------------------------------------------------------------------
__global__ __launch_bounds__(256) void prep_kernel(
    const float* __restrict__ x, const float* __restrict__ qkv_w,
    const float* __restrict__ g1_w, const float* __restrict__ qkv_b,
    const float* __restrict__ g1_b, const float* __restrict__ proj_w,
    unsigned short* __restrict__ xb, unsigned short* __restrict__ wT,
    unsigned short* __restrict__ pT, float* __restrict__ bias_ext)
{
    const int blk = blockIdx.x, tid = threadIdx.x;
    if (blk < 2048) {
        int base = blk * 1024 + tid * 4;
        float4 v = *(const float4*)(x + base);
        ushort4 o; o.x = f2bf(v.x); o.y = f2bf(v.y); o.z = f2bf(v.z); o.w = f2bf(v.w);
        *(ushort4*)(xb + base) = o;
    } else if (blk < 2104) {
        int n = (blk - 2048) * 8 + (tid >> 5);
        int kq = tid & 31;
        float f0, f1, f2, f3;
        if (n < 384) {
            f0 = qkv_w[(kq*4+0)*384 + n]; f1 = qkv_w[(kq*4+1)*384 + n];
            f2 = qkv_w[(kq*4+2)*384 + n]; f3 = qkv_w[(kq*4+3)*384 + n];
        } else {
            int nn = n - 384;
            f0 = g1_w[(kq*4+0)*64 + nn]; f1 = g1_w[(kq*4+1)*64 + nn];
            f2 = g1_w[(kq*4+2)*64 + nn]; f3 = g1_w[(kq*4+3)*64 + nn];
        }
        ushort4 o; o.x = f2bf(f0); o.y = f2bf(f1); o.z = f2bf(f2); o.w = f2bf(f3);
        *(ushort4*)(wT + n*128 + kq*4) = o;
    } else if (blk < 2120) {
        int n = (blk - 2104) * 8 + (tid >> 5);
        int kq = tid & 31;
        ushort4 o;
        o.x = f2bf(proj_w[(kq*4+0)*128 + n]);
        o.y = f2bf(proj_w[(kq*4+1)*128 + n]);
        o.z = f2bf(proj_w[(kq*4+2)*128 + n]);
        o.w = f2bf(proj_w[(kq*4+3)*128 + n]);
        *(ushort4*)(pT + n*128 + kq*4) = o;
    } else {
        for (int idx = tid; idx < 448; idx += 256)
            bias_ext[idx] = (idx < 384) ? qkv_b[idx] : g1_b[idx - 384];
    }
}

// ---------------------------------------------------------------------------
// GEMM 1 (fused): qkvb[pix][384] bf16 = bf16(x @ W + b), q cols scaled.
// nt==6 block computes gate instead of storing.  (unchanged from round 4)
// ---------------------------------------------------------------------------
__global__ __launch_bounds__(256) void gemm_qkvh_fused(
    const unsigned short* __restrict__ xb, const unsigned short* __restrict__ wT,
    const float* __restrict__ bias_ext, const float* __restrict__ g2_w,
    const float* __restrict__ g2_b, unsigned short* __restrict__ qkvb,
    float* __restrict__ gate)
{
    __shared__ __align__(16) unsigned short As[64*128];
    __shared__ __align__(16) unsigned short Bs[64*128];
    const int nt = blockIdx.x;
    const int n0 = nt * 64;
    const int m0 = blockIdx.y * 64;
    const int tid = threadIdx.x;

#pragma unroll
    for (int it = 0; it < 4; it++) {
        int idx = tid + it*256, row = idx >> 4, c = idx & 15;
        uint4 v = *(const uint4*)(xb + (size_t)(m0+row)*128 + c*8);
        *(uint4*)(As + row*128 + ((c ^ (row&7)) << 3)) = v;
    }
#pragma unroll
    for (int it = 0; it < 4; it++) {
        int idx = tid + it*256, row = idx >> 4, c = idx & 15;
        uint4 v = *(const uint4*)(wT + (size_t)(n0+row)*128 + c*8);
        *(uint4*)(Bs + row*128 + ((c ^ (row&7)) << 3)) = v;
    }
    __syncthreads();

    const int wave = tid >> 6, lane = tid & 63;
    const int l15 = lane & 15, quad = lane >> 4;
    const int wm = (wave & 1) * 32, wn = (wave >> 1) * 32;

    f32x4 acc[2][2] = {};
#pragma unroll
    for (int ks = 0; ks < 4; ks++) {
        bf16x8 af[2], bq[2];
#pragma unroll
        for (int mt = 0; mt < 2; mt++) {
            int m = wm + mt*16 + l15;
            af[mt] = *(const bf16x8*)(As + m*128 + (((ks*4+quad) ^ (m&7)) << 3));
        }
#pragma unroll
        for (int ntl = 0; ntl < 2; ntl++) {
            int n = wn + ntl*16 + l15;
            bq[ntl] = *(const bf16x8*)(Bs + n*128 + (((ks*4+quad) ^ (n&7)) << 3));
        }
#pragma unroll
        for (int mt = 0; mt < 2; mt++)
#pragma unroll
            for (int ntl = 0; ntl < 2; ntl++)
                acc[mt][ntl] = __builtin_amdgcn_mfma_f32_16x16x32_bf16(
                    af[mt], bq[ntl], acc[mt][ntl], 0, 0, 0);
    }
    __syncthreads();   // As/Bs dead; reuse below

    if (nt < 6) {
        unsigned short* Cs = (unsigned short*)As;   // 64x64 bf16
#pragma unroll
        for (int ntl = 0; ntl < 2; ntl++) {
            int nl = wn + ntl*16 + l15;
            int ng = n0 + nl;
            float qs = (ng < 128) ? QSCALE : 1.0f;
            float bv = bias_ext[ng];
#pragma unroll
            for (int mt = 0; mt < 2; mt++)
#pragma unroll
                for (int r = 0; r < 4; r++) {
                    int ml = wm + mt*16 + quad*4 + r;
                    Cs[ml*64 + nl] = f2bf((acc[mt][ntl][r] + bv) * qs);
                }
        }
        __syncthreads();
        int row = tid >> 2, part = tid & 3;
        uint4 a = *(const uint4*)(Cs + row*64 + part*16);
        uint4 b = *(const uint4*)(Cs + row*64 + part*16 + 8);
        unsigned short* dst = qkvb + (size_t)(m0+row)*384 + n0 + part*16;
        *(uint4*)dst = a;
        *(uint4*)(dst + 8) = b;
    } else {
        float* gpart = (float*)Bs;   // [2][64]
        float rs[2][4];
#pragma unroll
        for (int mt = 0; mt < 2; mt++)
#pragma unroll
            for (int r = 0; r < 4; r++) rs[mt][r] = 0.0f;
#pragma unroll
        for (int ntl = 0; ntl < 2; ntl++) {
            int nl = wn + ntl*16 + l15;
            float bv = bias_ext[384 + nl];
            float gw = g2_w[nl];
#pragma unroll
            for (int mt = 0; mt < 2; mt++)
#pragma unroll
                for (int r = 0; r < 4; r++) {
                    float h = acc[mt][ntl][r] + bv;
                    rs[mt][r] += fmaxf(h, 0.0f) * gw;
                }
        }
#pragma unroll
        for (int off = 1; off <= 8; off <<= 1)
#pragma unroll
            for (int mt = 0; mt < 2; mt++)
#pragma unroll
                for (int r = 0; r < 4; r++)
                    rs[mt][r] += __shfl_xor(rs[mt][r], off);
        if (l15 == 0) {
#pragma unroll
            for (int mt = 0; mt < 2; mt++)
#pragma unroll
                for (int r = 0; r < 4; r++)
                    gpart[(wave >> 1)*64 + wm + mt*16 + quad*4 + r] = rs[mt][r];
        }
        __syncthreads();
        if (tid < 64) {
            float g = gpart[tid] + gpart[64 + tid] + g2_b[0];
            gate[m0 + tid] = 1.0f / (1.0f + __expf(-g));
        }
    }
}

// ---------------------------------------------------------------------------
// attention: lane = pixel.  Block = (batch, 8x8 tile, head pair), 128 thr =
// 2 waves, wave = one head, lane = one of 64 pixels.  Per-lane private
// online softmax over 49 keys: zero shuffles, zero idle lanes.
// LDS: kvs[196 pos][136 hw]  row = [K h0|K h1|V h0|V h1|pad8] (272 B stride
// -> 4-dword bank rotation per pos -> gathered b128 reads at the 8-cyc
// floor).  53.3 KB + rpb -> 2 blocks/CU.  grid 512 x 128.
// ---------------------------------------------------------------------------
__global__ __launch_bounds__(128) void attn_kernel(
    const unsigned short* __restrict__ qkvb, const float* __restrict__ rpb,
    unsigned short* __restrict__ attnb)
{
    __shared__ __align__(16) unsigned short kvs[196 * 136];
    __shared__ float rpb_lds[2 * 169];

    const int blk = blockIdx.x;
    const int pr = blk & 1;               // head pair
    const int tile = (blk >> 1) & 63;
    const int b = blk >> 7;
    const int ti0 = (tile >> 3) * 8, tj0 = (tile & 7) * 8;
    int wr0 = ti0 - 3; if (wr0 < 0) wr0 = 0;
    int wc0 = tj0 - 3; if (wc0 < 0) wc0 = 0;

    const int tid = threadIdx.x;

    for (int t = tid; t < 338; t += 128) rpb_lds[t] = rpb[pr * 338 + t];

    // stage K/V: 196 positions x 16 chunks (16B).  t<8: K dims pr*64..+63,
    // t>=8: V same slice.  dst row stride 136 hw.
    for (int idx = tid; idx < 196 * 16; idx += 128) {
        int pos = idx >> 4, t = idx & 15;
        int wr = pos / 14, wc = pos - wr * 14;
        int gr = wr0 + wr; if (gr > 63) gr = 63;
        int gc = wc0 + wc; if (gc > 63) gc = 63;
        size_t gp = (size_t)(((b << 6) + gr) << 6) + gc;
        int src = 128 + ((t >> 3) << 7) + pr * 64 + ((t & 7) << 3);
        uint4 v = *(const uint4*)(qkvb + gp * 384 + src);
        *(uint4*)(kvs + pos * 136 + ((t >> 3) << 6) + ((t & 7) << 3)) = v;
    }
    __syncthreads();

    const int hh = tid >> 6, lane = tid & 63;
    const int h = pr * 2 + hh;
    const int pi = lane >> 3, pj = lane & 7;
    const int i = ti0 + pi, j = tj0 + pj;
    int sh = i - 3; sh = sh < 0 ? 0 : (sh > 57 ? 57 : sh);
    int sw = j - 3; sw = sw < 0 ? 0 : (sw > 57 ? 57 : sw);
    const int dr = sh - wr0, dc = sw - wc0;
    const size_t gp = (size_t)(((b << 6) + i) << 6) + j;

    // Q: 32 dims, unpacked to fp32 (q-scale already applied in gemm1)
    unsigned int qu[16];
    const unsigned short* qptr = qkvb + gp * 384 + h * 32;
    *(uint4*)(qu + 0)  = *(const uint4*)(qptr + 0);
    *(uint4*)(qu + 4)  = *(const uint4*)(qptr + 8);
    *(uint4*)(qu + 8)  = *(const uint4*)(qptr + 16);
    *(uint4*)(qu + 12) = *(const uint4*)(qptr + 24);
    float qf[32];
#pragma unroll
    for (int p = 0; p < 16; p++) {
        qf[2*p]   = bflo(qu[p]);
        qf[2*p+1] = bfhi(qu[p]);
    }

    float acc[32];
#pragma unroll
    for (int d = 0; d < 32; d++) acc[d] = 0.0f;
    float ssum = 0.0f;

    const float* rl = rpb_lds + hh * 169;
    const int rbase = (sh - i + 6) * 13 + (sw - j + 6);
    const int hwbase = (dr * 14 + dc) * 136 + hh * 32;

    for (int kr = 0; kr < 7; kr++) {
        int hw = hwbase + kr * (14 * 136);
        int ri = rbase + kr * 13;
#pragma unroll
        for (int kc = 0; kc < 7; kc++) {
            const unsigned short* kp = kvs + hw;
            unsigned int ku[16];
            *(uint4*)(ku + 0)  = *(const uint4*)(kp + 0);
            *(uint4*)(ku + 4)  = *(const uint4*)(kp + 8);
            *(uint4*)(ku + 8)  = *(const uint4*)(kp + 16);
            *(uint4*)(ku + 12) = *(const uint4*)(kp + 24);
            float s0 = rl[ri + kc], s1 = 0.0f;
#pragma unroll
            for (int p = 0; p < 8; p++) {
                s0 += qf[2*p]      * bflo(ku[p])     + qf[2*p+1]  * bfhi(ku[p]);
                s1 += qf[2*p+16]   * bflo(ku[p+8])   + qf[2*p+17] * bfhi(ku[p+8]);
            }
            float e = __expf(s0 + s1);   // max-free: scores bounded (~|s|<1)
            ssum += e;
            unsigned int vu[16];
            *(uint4*)(vu + 0)  = *(const uint4*)(kp + 64);
            *(uint4*)(vu + 4)  = *(const uint4*)(kp + 72);
            *(uint4*)(vu + 8)  = *(const uint4*)(kp + 80);
            *(uint4*)(vu + 12) = *(const uint4*)(kp + 88);
#pragma unroll
            for (int p = 0; p < 16; p++) {
                acc[2*p]   += e * bflo(vu[p]);
                acc[2*p+1] += e * bfhi(vu[p]);
            }
            hw += 136;
        }
    }

    const float inv = 1.0f / ssum;
    unsigned int o[16];
#pragma unroll
    for (int p = 0; p < 16; p++) {
        unsigned int lo = f2bf(acc[2*p] * inv);
        unsigned int hi = f2bf(acc[2*p+1] * inv);
        o[p] = lo | (hi << 16);
    }
    unsigned short* op = attnb + gp * 128 + h * 32;
    *(uint4*)(op + 0)  = *(const uint4*)(o + 0);
    *(uint4*)(op + 8)  = *(const uint4*)(o + 4);
    *(uint4*)(op + 16) = *(const uint4*)(o + 8);
    *(uint4*)(op + 24) = *(const uint4*)(o + 12);
}

// ---------------------------------------------------------------------------
// GEMM 2: out = (attnb @ pT^T + proj_b) * gate + x.  (unchanged from round 4)
// ---------------------------------------------------------------------------
__global__ __launch_bounds__(256) void gemm_proj_mfma(
    const unsigned short* __restrict__ ab, const unsigned short* __restrict__ pT,
    const float* __restrict__ proj_b, const float* __restrict__ gate,
    const float* __restrict__ x, float* __restrict__ out)
{
    __shared__ __align__(16) unsigned short As[64*128];
    __shared__ __align__(16) unsigned short Bs[64*128];
    const int n0 = blockIdx.x * 64;
    const int m0 = blockIdx.y * 64;
    const int tid = threadIdx.x;

#pragma unroll
    for (int it = 0; it < 4; it++) {
        int idx = tid + it*256, row = idx >> 4, c = idx & 15;
        uint4 v = *(const uint4*)(ab + (size_t)(m0+row)*128 + c*8);
        *(uint4*)(As + row*128 + ((c ^ (row&7)) << 3)) = v;
    }
#pragma unroll
    for (int it = 0; it < 4; it++) {
        int idx = tid + it*256, row = idx >> 4, c = idx & 15;
        uint4 v = *(const uint4*)(pT + (size_t)(n0+row)*128 + c*8);
        *(uint4*)(Bs + row*128 + ((c ^ (row&7)) << 3)) = v;
    }
    __syncthreads();

    const int wave = tid >> 6, lane = tid & 63;
    const int l15 = lane & 15, quad = lane >> 4;
    const int wm = (wave & 1) * 32, wn = (wave >> 1) * 32;

    f32x4 acc[2][2] = {};
#pragma unroll
    for (int ks = 0; ks < 4; ks++) {
        bf16x8 af[2], bq[2];
#pragma unroll
        for (int mt = 0; mt < 2; mt++) {
            int m = wm + mt*16 + l15;
            af[mt] = *(const bf16x8*)(As + m*128 + (((ks*4+quad) ^ (m&7)) << 3));
        }
#pragma unroll
        for (int ntl = 0; ntl < 2; ntl++) {
            int n = wn + ntl*16 + l15;
            bq[ntl] = *(const bf16x8*)(Bs + n*128 + (((ks*4+quad) ^ (n&7)) << 3));
        }
#pragma unroll
        for (int mt = 0; mt < 2; mt++)
#pragma unroll
            for (int ntl = 0; ntl < 2; ntl++)
                acc[mt][ntl] = __builtin_amdgcn_mfma_f32_16x16x32_bf16(
                    af[mt], bq[ntl], acc[mt][ntl], 0, 0, 0);
    }
    __syncthreads();

    float* Cs = (float*)As;   // 64x64 f32
#pragma unroll
    for (int ntl = 0; ntl < 2; ntl++) {
        int nl = wn + ntl*16 + l15;
        float bv = proj_b[n0 + nl];
#pragma unroll
        for (int mt = 0; mt < 2; mt++)
#pragma unroll
            for (int r = 0; r < 4; r++) {
                int ml = wm + mt*16 + quad*4 + r;
                Cs[ml*64 + nl] = acc[mt][ntl][r] + bv;
            }
    }
    __syncthreads();
    int row = tid >> 2, part = tid & 3;
    float gv = gate[m0 + row];
    const float* xr = x + (size_t)(m0+row)*128 + n0 + part*16;
    float* orow = out + (size_t)(m0+row)*128 + n0 + part*16;
#pragma unroll
    for (int q = 0; q < 4; q++) {
        float4 cv = *(const float4*)(Cs + row*64 + part*16 + q*4);
        float4 xv = *(const float4*)(xr + q*4);
        float4 o;
        o.x = cv.x * gv + xv.x; o.y = cv.y * gv + xv.y;
        o.z = cv.z * gv + xv.z; o.w = cv.w * gv + xv.w;
        *(float4*)(orow + q*4) = o;
    }
}

// ---------------------------------------------------------------------------
extern "C" void kernel_launch(void* const* d_in, const int* in_sizes, int n_in,
                              void* d_out, int out_size, void* d_ws, size_t ws_size,
                              hipStream_t stream)
{
    const float* x      = (const float*)d_in[0];
    const float* qkv_w  = (const float*)d_in[1];
    const float* qkv_b  = (const float*)d_in[2];
    const float* proj_w = (const float*)d_in[3];
    const float* proj_b = (const float*)d_in[4];
    const float* rpb    = (const float*)d_in[5];
    const float* g1_w   = (const float*)d_in[6];
    const float* g1_b   = (const float*)d_in[7];
    const float* g2_w   = (const float*)d_in[8];
    const float* g2_b   = (const float*)d_in[9];
    float* out = (float*)d_out;

    float* ws        = (float*)d_ws;
    float* gate      = ws;                          // 16384 f32
    float* bias_ext  = gate + 16384;                // 448 f32
    unsigned short* xb    = (unsigned short*)(bias_ext + 448);  // 16384*128
    unsigned short* wT    = xb + 2097152;           // 448*128
    unsigned short* pT    = wT + 57344;             // 128*128
    unsigned short* qkvb  = pT + 16384;             // 16384*384 bf16
    unsigned short* attnb = qkvb + 6291456;         // 16384*128 bf16

    (void)in_sizes; (void)n_in; (void)out_size; (void)ws_size;

    prep_kernel<<<2121, 256, 0, stream>>>(x, qkv_w, g1_w, qkv_b, g1_b, proj_w,
                                          xb, wT, pT, bias_ext);
    gemm_qkvh_fused<<<dim3(7, 256), 256, 0, stream>>>(xb, wT, bias_ext,
                                                      g2_w, g2_b, qkvb, gate);
    attn_kernel<<<512, 128, 0, stream>>>(qkvb, rpb, attnb);
    gemm_proj_mfma<<<dim3(2, 256), 256, 0, stream>>>(attnb, pT, proj_b, gate, x, out);
}